// Round 2
// baseline (985.359 us; speedup 1.0000x reference)
//
#include <hip/hip_runtime.h>

#define N_P 200000
#define N_A 100000
#define DD  64
#define HH  32
#define NE  1000000

// ---------------- degree counting ----------------
__global__ __launch_bounds__(256) void count_deg_k(const int* __restrict__ dst,
                                                   int* __restrict__ deg, int n) {
    int e = blockIdx.x * 256 + threadIdx.x;
    if (e < n) atomicAdd(&deg[dst[e]], 1);
}

__global__ __launch_bounds__(256) void deg_to_inv_k(int* __restrict__ buf, int n) {
    int i = blockIdx.x * 256 + threadIdx.x;
    if (i < n) {
        int d = buf[i];
        float v = 1.0f / (float)(d < 1 ? 1 : d);
        buf[i] = __float_as_int(v);
    }
}

// ---------------- dense row transform helper ----------------
template <int K>
__device__ inline void mm_row(const float* xr, const float* sW, float* acc) {
#pragma unroll
    for (int k = 0; k < K; ++k) {
        float xk = xr[k];
        const float4* wrow = reinterpret_cast<const float4*>(sW + k * HH);
#pragma unroll
        for (int c = 0; c < 8; ++c) {
            float4 w = wrow[c];
            acc[c * 4 + 0] = fmaf(xk, w.x, acc[c * 4 + 0]);
            acc[c * 4 + 1] = fmaf(xk, w.y, acc[c * 4 + 1]);
            acc[c * 4 + 2] = fmaf(xk, w.z, acc[c * 4 + 2]);
            acc[c * 4 + 3] = fmaf(xk, w.w, acc[c * 4 + 3]);
        }
    }
}

__device__ inline void store_row(float* out, const float* acc) {
    float4* o = reinterpret_cast<float4*>(out);
#pragma unroll
    for (int c = 0; c < 8; ++c)
        o[c] = make_float4(acc[4 * c], acc[4 * c + 1], acc[4 * c + 2], acc[4 * c + 3]);
}

// layer-1 paper: y_pc = x@W1l_c ; y_pr = x@W1l_r ; h1p = x@(W1r_c+W1r_w) + (b1_c+b1_w)
__global__ __launch_bounds__(256) void transform_p1_k(
    const float* __restrict__ x,
    const float* __restrict__ Wlc, const float* __restrict__ Wlr,
    const float* __restrict__ Wrc, const float* __restrict__ Wrw,
    const float* __restrict__ bc, const float* __restrict__ bw,
    float* __restrict__ y_pc, float* __restrict__ y_pr,
    float* __restrict__ h1p, int n) {
    __shared__ __align__(16) float sWc[DD * HH];
    __shared__ __align__(16) float sWr[DD * HH];
    __shared__ __align__(16) float sWs[DD * HH];
    __shared__ __align__(16) float sb[HH];
    int t = threadIdx.x;
    for (int i = t; i < DD * HH; i += 256) {
        sWc[i] = Wlc[i];
        sWr[i] = Wlr[i];
        sWs[i] = Wrc[i] + Wrw[i];
    }
    if (t < HH) sb[t] = bc[t] + bw[t];
    __syncthreads();
    int row = blockIdx.x * 256 + t;
    if (row >= n) return;
    float xr[DD];
    const float4* xp = reinterpret_cast<const float4*>(x + (size_t)row * DD);
#pragma unroll
    for (int i = 0; i < DD / 4; ++i) {
        float4 v = xp[i];
        xr[4 * i] = v.x; xr[4 * i + 1] = v.y; xr[4 * i + 2] = v.z; xr[4 * i + 3] = v.w;
    }
    float acc[HH];
#pragma unroll
    for (int c = 0; c < HH; ++c) acc[c] = 0.f;
    mm_row<DD>(xr, sWc, acc);
    store_row(y_pc + (size_t)row * HH, acc);
#pragma unroll
    for (int c = 0; c < HH; ++c) acc[c] = 0.f;
    mm_row<DD>(xr, sWr, acc);
    store_row(y_pr + (size_t)row * HH, acc);
#pragma unroll
    for (int c = 0; c < HH; ++c) acc[c] = sb[c];
    mm_row<DD>(xr, sWs, acc);
    store_row(h1p + (size_t)row * HH, acc);
}

// layer-1 author: y_aw = x@W1l_w ; h1a = x@W1r_rev + b1_rev
__global__ __launch_bounds__(256) void transform_a1_k(
    const float* __restrict__ x,
    const float* __restrict__ Wlw, const float* __restrict__ Wrr,
    const float* __restrict__ br,
    float* __restrict__ y_aw, float* __restrict__ h1a, int n) {
    __shared__ __align__(16) float sWl[DD * HH];
    __shared__ __align__(16) float sWr[DD * HH];
    __shared__ __align__(16) float sb[HH];
    int t = threadIdx.x;
    for (int i = t; i < DD * HH; i += 256) {
        sWl[i] = Wlw[i];
        sWr[i] = Wrr[i];
    }
    if (t < HH) sb[t] = br[t];
    __syncthreads();
    int row = blockIdx.x * 256 + t;
    if (row >= n) return;
    float xr[DD];
    const float4* xp = reinterpret_cast<const float4*>(x + (size_t)row * DD);
#pragma unroll
    for (int i = 0; i < DD / 4; ++i) {
        float4 v = xp[i];
        xr[4 * i] = v.x; xr[4 * i + 1] = v.y; xr[4 * i + 2] = v.z; xr[4 * i + 3] = v.w;
    }
    float acc[HH];
#pragma unroll
    for (int c = 0; c < HH; ++c) acc[c] = 0.f;
    mm_row<DD>(xr, sWl, acc);
    store_row(y_aw + (size_t)row * HH, acc);
#pragma unroll
    for (int c = 0; c < HH; ++c) acc[c] = sb[c];
    mm_row<DD>(xr, sWr, acc);
    store_row(h1a + (size_t)row * HH, acc);
}

// layer-2 paper: r = relu(h1p); z_p = r@W2l_c ; out = r@(W2r_c+W2r_w) + (b2_c+b2_w)
__global__ __launch_bounds__(256) void transform_p2_k(
    const float* __restrict__ h1p,
    const float* __restrict__ Wlc, const float* __restrict__ Wrc,
    const float* __restrict__ Wrw,
    const float* __restrict__ bc, const float* __restrict__ bw,
    float* __restrict__ z_p, float* __restrict__ outp, int n) {
    __shared__ __align__(16) float sWl[HH * HH];
    __shared__ __align__(16) float sWs[HH * HH];
    __shared__ __align__(16) float sb[HH];
    int t = threadIdx.x;
    for (int i = t; i < HH * HH; i += 256) {
        sWl[i] = Wlc[i];
        sWs[i] = Wrc[i] + Wrw[i];
    }
    if (t < HH) sb[t] = bc[t] + bw[t];
    __syncthreads();
    int row = blockIdx.x * 256 + t;
    if (row >= n) return;
    float xr[HH];
    const float4* xp = reinterpret_cast<const float4*>(h1p + (size_t)row * HH);
#pragma unroll
    for (int i = 0; i < HH / 4; ++i) {
        float4 v = xp[i];
        xr[4 * i]     = v.x > 0.f ? v.x : 0.f;
        xr[4 * i + 1] = v.y > 0.f ? v.y : 0.f;
        xr[4 * i + 2] = v.z > 0.f ? v.z : 0.f;
        xr[4 * i + 3] = v.w > 0.f ? v.w : 0.f;
    }
    float acc[HH];
#pragma unroll
    for (int c = 0; c < HH; ++c) acc[c] = 0.f;
    mm_row<HH>(xr, sWl, acc);
    store_row(z_p + (size_t)row * HH, acc);
#pragma unroll
    for (int c = 0; c < HH; ++c) acc[c] = sb[c];
    mm_row<HH>(xr, sWs, acc);
    store_row(outp + (size_t)row * HH, acc);
}

// layer-2 author: z_a = relu(h1a)@W2l_w
__global__ __launch_bounds__(256) void transform_a2_k(
    const float* __restrict__ h1a, const float* __restrict__ Wlw,
    float* __restrict__ z_a, int n) {
    __shared__ __align__(16) float sWl[HH * HH];
    int t = threadIdx.x;
    for (int i = t; i < HH * HH; i += 256) sWl[i] = Wlw[i];
    __syncthreads();
    int row = blockIdx.x * 256 + t;
    if (row >= n) return;
    float xr[HH];
    const float4* xp = reinterpret_cast<const float4*>(h1a + (size_t)row * HH);
#pragma unroll
    for (int i = 0; i < HH / 4; ++i) {
        float4 v = xp[i];
        xr[4 * i]     = v.x > 0.f ? v.x : 0.f;
        xr[4 * i + 1] = v.y > 0.f ? v.y : 0.f;
        xr[4 * i + 2] = v.z > 0.f ? v.z : 0.f;
        xr[4 * i + 3] = v.w > 0.f ? v.w : 0.f;
    }
    float acc[HH];
#pragma unroll
    for (int c = 0; c < HH; ++c) acc[c] = 0.f;
    mm_row<HH>(xr, sWl, acc);
    store_row(z_a + (size_t)row * HH, acc);
}

// scatter-add with per-dst mean pre-scaling: acc[dst] += y[src] * inv[dst]
// 32 lanes per edge (one per channel)
__global__ __launch_bounds__(256) void scatter_k(
    const float* __restrict__ y, const int* __restrict__ src,
    const int* __restrict__ dst, const float* __restrict__ inv,
    float* __restrict__ acc, int n) {
    int idx = blockIdx.x * 256 + threadIdx.x;
    int e = idx >> 5;
    int lane = idx & 31;
    if (e >= n) return;
    int s = src[e];
    int d = dst[e];
    float v = y[(size_t)s * HH + lane] * inv[d];
    atomicAdd(&acc[(size_t)d * HH + lane], v);
}

extern "C" void kernel_launch(void* const* d_in, const int* in_sizes, int n_in,
                              void* d_out, int out_size, void* d_ws, size_t ws_size,
                              hipStream_t stream) {
    const float* x_p  = (const float*)d_in[0];
    const float* x_a  = (const float*)d_in[1];
    const int* c_src  = (const int*)d_in[2];
    const int* c_dst  = (const int*)d_in[3];
    const int* w_src  = (const int*)d_in[4];
    const int* w_dst  = (const int*)d_in[5];
    const int* r_src  = (const int*)d_in[6];
    const int* r_dst  = (const int*)d_in[7];
    const float* W1l_c = (const float*)d_in[8];
    const float* W1r_c = (const float*)d_in[9];
    const float* b1_c  = (const float*)d_in[10];
    const float* W1l_w = (const float*)d_in[11];
    const float* W1r_w = (const float*)d_in[12];
    const float* b1_w  = (const float*)d_in[13];
    const float* W1l_r = (const float*)d_in[14];
    const float* W1r_r = (const float*)d_in[15];
    const float* b1_r  = (const float*)d_in[16];
    const float* W2l_c = (const float*)d_in[17];
    const float* W2r_c = (const float*)d_in[18];
    const float* b2_c  = (const float*)d_in[19];
    const float* W2l_w = (const float*)d_in[20];
    const float* W2r_w = (const float*)d_in[21];
    const float* b2_w  = (const float*)d_in[22];

    // workspace layout (floats): inv_c[N_P] inv_w[N_P] inv_r[N_A]
    //   y_pc[N_P*H] y_pr[N_P*H] y_aw[N_A*H] h1p[N_P*H] h1a[N_A*H]  ~= 104.4 MB
    const size_t need = (size_t)(2 * N_P + N_A) + 3 * (size_t)N_P * HH
                      + 2 * (size_t)N_A * HH;
    if (ws_size < need * sizeof(float)) return;  // fail loudly (validation) not OOB

    float* ws    = (float*)d_ws;
    float* inv_c = ws;                            // N_P
    float* inv_w = inv_c + N_P;                   // N_P
    float* inv_r = inv_w + N_P;                   // N_A
    float* y_pc  = inv_r + N_A;                   // N_P*H
    float* y_pr  = y_pc + (size_t)N_P * HH;       // N_P*H
    float* y_aw  = y_pr + (size_t)N_P * HH;       // N_A*H
    float* h1p   = y_aw + (size_t)N_A * HH;       // N_P*H
    float* h1a   = h1p + (size_t)N_P * HH;        // N_A*H
    float* z_p   = y_pc;                          // reuse after L1 scatters
    float* z_a   = y_aw;                          // reuse after L1 scatters
    float* outp  = (float*)d_out;

    // degrees -> reciprocals
    hipMemsetAsync(inv_c, 0, (size_t)(2 * N_P + N_A) * sizeof(float), stream);
    count_deg_k<<<(NE + 255) / 256, 256, 0, stream>>>(c_dst, (int*)inv_c, NE);
    count_deg_k<<<(NE + 255) / 256, 256, 0, stream>>>(w_dst, (int*)inv_w, NE);
    count_deg_k<<<(NE + 255) / 256, 256, 0, stream>>>(r_dst, (int*)inv_r, NE);
    deg_to_inv_k<<<(2 * N_P + N_A + 255) / 256, 256, 0, stream>>>((int*)inv_c, 2 * N_P + N_A);

    // layer-1 dense transforms (fold self terms + biases into scatter accumulators)
    transform_p1_k<<<(N_P + 255) / 256, 256, 0, stream>>>(
        x_p, W1l_c, W1l_r, W1r_c, W1r_w, b1_c, b1_w, y_pc, y_pr, h1p, N_P);
    transform_a1_k<<<(N_A + 255) / 256, 256, 0, stream>>>(
        x_a, W1l_w, W1r_r, b1_r, y_aw, h1a, N_A);

    // layer-1 scatters
    const int sg = (NE * 32 + 255) / 256;
    scatter_k<<<sg, 256, 0, stream>>>(y_pc, c_src, c_dst, inv_c, h1p, NE);
    scatter_k<<<sg, 256, 0, stream>>>(y_aw, w_src, w_dst, inv_w, h1p, NE);
    scatter_k<<<sg, 256, 0, stream>>>(y_pr, r_src, r_dst, inv_r, h1a, NE);

    // layer-2 dense transforms (relu fused into the read)
    transform_p2_k<<<(N_P + 255) / 256, 256, 0, stream>>>(
        h1p, W2l_c, W2r_c, W2r_w, b2_c, b2_w, z_p, outp, N_P);
    transform_a2_k<<<(N_A + 255) / 256, 256, 0, stream>>>(h1a, W2l_w, z_a, N_A);

    // layer-2 scatters into d_out
    scatter_k<<<sg, 256, 0, stream>>>(z_p, c_src, c_dst, inv_c, outp, NE);
    scatter_k<<<sg, 256, 0, stream>>>(z_a, w_src, w_dst, inv_w, outp, NE);
}

// Round 3
// 952.226 us; speedup vs baseline: 1.0348x; 1.0348x over previous
//
#include <hip/hip_runtime.h>

#define N_P 200000
#define N_A 100000
#define DD  64
#define HH  32
#define CH  16      // column half width (HH/2)
#define NE  1000000

// ---------------- degree counting ----------------
__global__ __launch_bounds__(256) void count_deg_k(const int* __restrict__ dst,
                                                   int* __restrict__ deg, int n) {
    int e = blockIdx.x * 256 + threadIdx.x;
    if (e < n) atomicAdd(&deg[dst[e]], 1);
}

__global__ __launch_bounds__(256) void deg_to_inv_k(int* __restrict__ buf, int n) {
    int i = blockIdx.x * 256 + threadIdx.x;
    if (i < n) {
        int d = buf[i];
        float v = 1.0f / (float)(d < 1 ? 1 : d);
        buf[i] = __float_as_int(v);
    }
}

// ---------------- dense row transform helpers ----------------
// acc[C] += xr[0..K) dot sW[k*C + c]  (sW column-sliced in LDS)
template <int K, int C>
__device__ inline void mm_row(const float* xr, const float* sW, float* acc) {
#pragma unroll
    for (int k = 0; k < K; ++k) {
        float xk = xr[k];
        const float4* wrow = reinterpret_cast<const float4*>(sW + k * C);
#pragma unroll
        for (int c = 0; c < C / 4; ++c) {
            float4 w = wrow[c];
            acc[c * 4 + 0] = fmaf(xk, w.x, acc[c * 4 + 0]);
            acc[c * 4 + 1] = fmaf(xk, w.y, acc[c * 4 + 1]);
            acc[c * 4 + 2] = fmaf(xk, w.z, acc[c * 4 + 2]);
            acc[c * 4 + 3] = fmaf(xk, w.w, acc[c * 4 + 3]);
        }
    }
}

template <int C>
__device__ inline void store_row(float* out, const float* acc) {
    float4* o = reinterpret_cast<float4*>(out);
#pragma unroll
    for (int c = 0; c < C / 4; ++c)
        o[c] = make_float4(acc[4 * c], acc[4 * c + 1], acc[4 * c + 2], acc[4 * c + 3]);
}

// layer-1 paper: y_pc = x@W1l_c ; y_pr = x@W1l_r ; h1p = x@(W1r_c+W1r_w) + (b1_c+b1_w)
// blockIdx.y in {0,1} selects 16-column half (halves LDS, doubles grid for occupancy)
__global__ __launch_bounds__(256) void transform_p1_k(
    const float* __restrict__ x,
    const float* __restrict__ Wlc, const float* __restrict__ Wlr,
    const float* __restrict__ Wrc, const float* __restrict__ Wrw,
    const float* __restrict__ bc, const float* __restrict__ bw,
    float* __restrict__ y_pc, float* __restrict__ y_pr,
    float* __restrict__ h1p, int n) {
    const int ch = blockIdx.y;            // column half
    const int c0 = ch * CH;
    __shared__ __align__(16) float sWc[DD * CH];
    __shared__ __align__(16) float sWr[DD * CH];
    __shared__ __align__(16) float sWs[DD * CH];
    __shared__ __align__(16) float sb[CH];
    int t = threadIdx.x;
    for (int i = t; i < DD * CH; i += 256) {
        int k = i / CH, c = i % CH;
        int g = k * HH + c0 + c;
        sWc[i] = Wlc[g];
        sWr[i] = Wlr[g];
        sWs[i] = Wrc[g] + Wrw[g];
    }
    if (t < CH) sb[t] = bc[c0 + t] + bw[c0 + t];
    __syncthreads();
    int row = blockIdx.x * 256 + t;
    if (row >= n) return;
    float xr[DD];
    const float4* xp = reinterpret_cast<const float4*>(x + (size_t)row * DD);
#pragma unroll
    for (int i = 0; i < DD / 4; ++i) {
        float4 v = xp[i];
        xr[4 * i] = v.x; xr[4 * i + 1] = v.y; xr[4 * i + 2] = v.z; xr[4 * i + 3] = v.w;
    }
    float acc[CH];
#pragma unroll
    for (int c = 0; c < CH; ++c) acc[c] = 0.f;
    mm_row<DD, CH>(xr, sWc, acc);
    store_row<CH>(y_pc + (size_t)row * HH + c0, acc);
#pragma unroll
    for (int c = 0; c < CH; ++c) acc[c] = 0.f;
    mm_row<DD, CH>(xr, sWr, acc);
    store_row<CH>(y_pr + (size_t)row * HH + c0, acc);
#pragma unroll
    for (int c = 0; c < CH; ++c) acc[c] = sb[c];
    mm_row<DD, CH>(xr, sWs, acc);
    store_row<CH>(h1p + (size_t)row * HH + c0, acc);
}

// layer-1 author: y_aw = x@W1l_w ; h1a = x@W1r_rev + b1_rev
__global__ __launch_bounds__(256) void transform_a1_k(
    const float* __restrict__ x,
    const float* __restrict__ Wlw, const float* __restrict__ Wrr,
    const float* __restrict__ br,
    float* __restrict__ y_aw, float* __restrict__ h1a, int n) {
    const int ch = blockIdx.y;
    const int c0 = ch * CH;
    __shared__ __align__(16) float sWl[DD * CH];
    __shared__ __align__(16) float sWr[DD * CH];
    __shared__ __align__(16) float sb[CH];
    int t = threadIdx.x;
    for (int i = t; i < DD * CH; i += 256) {
        int k = i / CH, c = i % CH;
        int g = k * HH + c0 + c;
        sWl[i] = Wlw[g];
        sWr[i] = Wrr[g];
    }
    if (t < CH) sb[t] = br[c0 + t];
    __syncthreads();
    int row = blockIdx.x * 256 + t;
    if (row >= n) return;
    float xr[DD];
    const float4* xp = reinterpret_cast<const float4*>(x + (size_t)row * DD);
#pragma unroll
    for (int i = 0; i < DD / 4; ++i) {
        float4 v = xp[i];
        xr[4 * i] = v.x; xr[4 * i + 1] = v.y; xr[4 * i + 2] = v.z; xr[4 * i + 3] = v.w;
    }
    float acc[CH];
#pragma unroll
    for (int c = 0; c < CH; ++c) acc[c] = 0.f;
    mm_row<DD, CH>(xr, sWl, acc);
    store_row<CH>(y_aw + (size_t)row * HH + c0, acc);
#pragma unroll
    for (int c = 0; c < CH; ++c) acc[c] = sb[c];
    mm_row<DD, CH>(xr, sWr, acc);
    store_row<CH>(h1a + (size_t)row * HH + c0, acc);
}

// layer-2 paper: r = relu(h1p); z_p = r@W2l_c ; out = r@(W2r_c+W2r_w) + (b2_c+b2_w)
__global__ __launch_bounds__(256) void transform_p2_k(
    const float* __restrict__ h1p,
    const float* __restrict__ Wlc, const float* __restrict__ Wrc,
    const float* __restrict__ Wrw,
    const float* __restrict__ bc, const float* __restrict__ bw,
    float* __restrict__ z_p, float* __restrict__ outp, int n) {
    const int ch = blockIdx.y;
    const int c0 = ch * CH;
    __shared__ __align__(16) float sWl[HH * CH];
    __shared__ __align__(16) float sWs[HH * CH];
    __shared__ __align__(16) float sb[CH];
    int t = threadIdx.x;
    for (int i = t; i < HH * CH; i += 256) {
        int k = i / CH, c = i % CH;
        int g = k * HH + c0 + c;
        sWl[i] = Wlc[g];
        sWs[i] = Wrc[g] + Wrw[g];
    }
    if (t < CH) sb[t] = bc[c0 + t] + bw[c0 + t];
    __syncthreads();
    int row = blockIdx.x * 256 + t;
    if (row >= n) return;
    float xr[HH];
    const float4* xp = reinterpret_cast<const float4*>(h1p + (size_t)row * HH);
#pragma unroll
    for (int i = 0; i < HH / 4; ++i) {
        float4 v = xp[i];
        xr[4 * i]     = v.x > 0.f ? v.x : 0.f;
        xr[4 * i + 1] = v.y > 0.f ? v.y : 0.f;
        xr[4 * i + 2] = v.z > 0.f ? v.z : 0.f;
        xr[4 * i + 3] = v.w > 0.f ? v.w : 0.f;
    }
    float acc[CH];
#pragma unroll
    for (int c = 0; c < CH; ++c) acc[c] = 0.f;
    mm_row<HH, CH>(xr, sWl, acc);
    store_row<CH>(z_p + (size_t)row * HH + c0, acc);
#pragma unroll
    for (int c = 0; c < CH; ++c) acc[c] = sb[c];
    mm_row<HH, CH>(xr, sWs, acc);
    store_row<CH>(outp + (size_t)row * HH + c0, acc);
}

// layer-2 author: z_a = relu(h1a)@W2l_w
__global__ __launch_bounds__(256) void transform_a2_k(
    const float* __restrict__ h1a, const float* __restrict__ Wlw,
    float* __restrict__ z_a, int n) {
    const int ch = blockIdx.y;
    const int c0 = ch * CH;
    __shared__ __align__(16) float sWl[HH * CH];
    int t = threadIdx.x;
    for (int i = t; i < HH * CH; i += 256) {
        int k = i / CH, c = i % CH;
        sWl[i] = Wlw[k * HH + c0 + c];
    }
    __syncthreads();
    int row = blockIdx.x * 256 + t;
    if (row >= n) return;
    float xr[HH];
    const float4* xp = reinterpret_cast<const float4*>(h1a + (size_t)row * HH);
#pragma unroll
    for (int i = 0; i < HH / 4; ++i) {
        float4 v = xp[i];
        xr[4 * i]     = v.x > 0.f ? v.x : 0.f;
        xr[4 * i + 1] = v.y > 0.f ? v.y : 0.f;
        xr[4 * i + 2] = v.z > 0.f ? v.z : 0.f;
        xr[4 * i + 3] = v.w > 0.f ? v.w : 0.f;
    }
    float acc[CH];
#pragma unroll
    for (int c = 0; c < CH; ++c) acc[c] = 0.f;
    mm_row<HH, CH>(xr, sWl, acc);
    store_row<CH>(z_a + (size_t)row * HH + c0, acc);
}

// scatter-add with per-dst mean pre-scaling: acc[dst] += y[src] * inv[dst]
// 32 lanes per edge (one per channel); native HW fp32 atomic (no CAS loop)
__global__ __launch_bounds__(256) void scatter_k(
    const float* __restrict__ y, const int* __restrict__ src,
    const int* __restrict__ dst, const float* __restrict__ inv,
    float* __restrict__ acc, int n) {
    int idx = blockIdx.x * 256 + threadIdx.x;
    int e = idx >> 5;
    int lane = idx & 31;
    if (e >= n) return;
    int s = src[e];
    int d = dst[e];
    float v = y[(size_t)s * HH + lane] * inv[d];
    unsafeAtomicAdd(&acc[(size_t)d * HH + lane], v);
}

extern "C" void kernel_launch(void* const* d_in, const int* in_sizes, int n_in,
                              void* d_out, int out_size, void* d_ws, size_t ws_size,
                              hipStream_t stream) {
    const float* x_p  = (const float*)d_in[0];
    const float* x_a  = (const float*)d_in[1];
    const int* c_src  = (const int*)d_in[2];
    const int* c_dst  = (const int*)d_in[3];
    const int* w_src  = (const int*)d_in[4];
    const int* w_dst  = (const int*)d_in[5];
    const int* r_src  = (const int*)d_in[6];
    const int* r_dst  = (const int*)d_in[7];
    const float* W1l_c = (const float*)d_in[8];
    const float* W1r_c = (const float*)d_in[9];
    const float* b1_c  = (const float*)d_in[10];
    const float* W1l_w = (const float*)d_in[11];
    const float* W1r_w = (const float*)d_in[12];
    const float* b1_w  = (const float*)d_in[13];
    const float* W1l_r = (const float*)d_in[14];
    const float* W1r_r = (const float*)d_in[15];
    const float* b1_r  = (const float*)d_in[16];
    const float* W2l_c = (const float*)d_in[17];
    const float* W2r_c = (const float*)d_in[18];
    const float* b2_c  = (const float*)d_in[19];
    const float* W2l_w = (const float*)d_in[20];
    const float* W2r_w = (const float*)d_in[21];
    const float* b2_w  = (const float*)d_in[22];

    // workspace layout (floats): inv_c[N_P] inv_w[N_P] inv_r[N_A]
    //   y_pc[N_P*H] y_pr[N_P*H] y_aw[N_A*H] h1p[N_P*H] h1a[N_A*H]  ~= 104.4 MB
    const size_t need = (size_t)(2 * N_P + N_A) + 3 * (size_t)N_P * HH
                      + 2 * (size_t)N_A * HH;
    if (ws_size < need * sizeof(float)) return;  // fail loudly (validation) not OOB

    float* ws    = (float*)d_ws;
    float* inv_c = ws;                            // N_P
    float* inv_w = inv_c + N_P;                   // N_P
    float* inv_r = inv_w + N_P;                   // N_A
    float* y_pc  = inv_r + N_A;                   // N_P*H
    float* y_pr  = y_pc + (size_t)N_P * HH;       // N_P*H
    float* y_aw  = y_pr + (size_t)N_P * HH;       // N_A*H
    float* h1p   = y_aw + (size_t)N_A * HH;       // N_P*H
    float* h1a   = h1p + (size_t)N_P * HH;        // N_A*H
    float* z_p   = y_pc;                          // reuse after L1 scatters
    float* z_a   = y_aw;                          // reuse after L1 scatters
    float* outp  = (float*)d_out;

    // degrees -> reciprocals
    hipMemsetAsync(inv_c, 0, (size_t)(2 * N_P + N_A) * sizeof(float), stream);
    count_deg_k<<<(NE + 255) / 256, 256, 0, stream>>>(c_dst, (int*)inv_c, NE);
    count_deg_k<<<(NE + 255) / 256, 256, 0, stream>>>(w_dst, (int*)inv_w, NE);
    count_deg_k<<<(NE + 255) / 256, 256, 0, stream>>>(r_dst, (int*)inv_r, NE);
    deg_to_inv_k<<<(2 * N_P + N_A + 255) / 256, 256, 0, stream>>>((int*)inv_c, 2 * N_P + N_A);

    // layer-1 dense transforms (fold self terms + biases into scatter accumulators)
    transform_p1_k<<<dim3((N_P + 255) / 256, 2), 256, 0, stream>>>(
        x_p, W1l_c, W1l_r, W1r_c, W1r_w, b1_c, b1_w, y_pc, y_pr, h1p, N_P);
    transform_a1_k<<<dim3((N_A + 255) / 256, 2), 256, 0, stream>>>(
        x_a, W1l_w, W1r_r, b1_r, y_aw, h1a, N_A);

    // layer-1 scatters
    const int sg = (NE * 32 + 255) / 256;
    scatter_k<<<sg, 256, 0, stream>>>(y_pc, c_src, c_dst, inv_c, h1p, NE);
    scatter_k<<<sg, 256, 0, stream>>>(y_aw, w_src, w_dst, inv_w, h1p, NE);
    scatter_k<<<sg, 256, 0, stream>>>(y_pr, r_src, r_dst, inv_r, h1a, NE);

    // layer-2 dense transforms (relu fused into the read)
    transform_p2_k<<<dim3((N_P + 255) / 256, 2), 256, 0, stream>>>(
        h1p, W2l_c, W2r_c, W2r_w, b2_c, b2_w, z_p, outp, N_P);
    transform_a2_k<<<dim3((N_A + 255) / 256, 2), 256, 0, stream>>>(h1a, W2l_w, z_a, N_A);

    // layer-2 scatters into d_out
    scatter_k<<<sg, 256, 0, stream>>>(z_p, c_src, c_dst, inv_c, outp, NE);
    scatter_k<<<sg, 256, 0, stream>>>(z_a, w_src, w_dst, inv_w, outp, NE);
}

// Round 5
// 887.724 us; speedup vs baseline: 1.1100x; 1.0727x over previous
//
#include <hip/hip_runtime.h>

typedef unsigned short u16;
typedef unsigned int   u32;

#define N_P 200000
#define N_A 100000
#define DD  64
#define HH  32
#define NE  1000000

// ---------- bf16 helpers (RNE) ----------
__device__ inline float bf2f(u16 u) { return __uint_as_float(((u32)u) << 16); }
__device__ inline u16 f2bf(float f) {
    u32 u = __float_as_uint(f);
    u += 0x7fffu + ((u >> 16) & 1u);
    return (u16)(u >> 16);
}

__device__ inline void store_bf16_row(u16* p, const float* acc) {
    u32 w[16];
#pragma unroll
    for (int i = 0; i < 16; ++i)
        w[i] = (u32)f2bf(acc[2 * i]) | ((u32)f2bf(acc[2 * i + 1]) << 16);
    uint4* o = (uint4*)p;
#pragma unroll
    for (int i = 0; i < 4; ++i) o[i] = make_uint4(w[4 * i], w[4 * i + 1], w[4 * i + 2], w[4 * i + 3]);
}

__device__ inline void store_f32_row(float* p, const float* acc) {
    float4* o = (float4*)p;
#pragma unroll
    for (int i = 0; i < HH / 4; ++i)
        o[i] = make_float4(acc[4 * i], acc[4 * i + 1], acc[4 * i + 2], acc[4 * i + 3]);
}

// ---------- CSR build ----------
__global__ __launch_bounds__(256) void count_deg_k(const int* __restrict__ dst,
                                                   int* __restrict__ deg, int n) {
    int e = blockIdx.x * 256 + threadIdx.x;
    if (e < n) atomicAdd(&deg[dst[e]], 1);
}

__global__ __launch_bounds__(256) void block_sum_k(const int* __restrict__ a,
                                                   int* __restrict__ bsum, int n) {
    __shared__ int s[256];
    int t = threadIdx.x, i = blockIdx.x * 256 + t;
    s[t] = (i < n) ? a[i] : 0;
    __syncthreads();
    for (int o = 128; o > 0; o >>= 1) {
        if (t < o) s[t] += s[t + o];
        __syncthreads();
    }
    if (t == 0) bsum[blockIdx.x] = s[0];
}

// single block, 256 threads, 4 items/thread serial + Hillis-Steele over thread totals
__global__ __launch_bounds__(256) void scan_chunks_k(const int* __restrict__ bsum,
                                                     int* __restrict__ boff, int n) {
    __shared__ int s[256];
    int t = threadIdx.x;
    int v[4];
    int tot = 0;
#pragma unroll
    for (int i = 0; i < 4; ++i) {
        int idx = t * 4 + i;
        v[i] = (idx < n) ? bsum[idx] : 0;
        tot += v[i];
    }
    s[t] = tot;
    __syncthreads();
    for (int o = 1; o < 256; o <<= 1) {
        int u = (t >= o) ? s[t - o] : 0;
        __syncthreads();
        s[t] += u;
        __syncthreads();
    }
    int run = s[t] - tot;  // exclusive prefix of this thread's chunk
#pragma unroll
    for (int i = 0; i < 4; ++i) {
        int idx = t * 4 + i;
        if (idx < n) boff[idx] = run;
        run += v[i];
    }
}

// degcur holds degrees on entry; becomes the fill cursor (== off) on exit
__global__ __launch_bounds__(256) void expand_k(int* __restrict__ degcur,
                                                const int* __restrict__ boff,
                                                int* __restrict__ off, int n, int total) {
    __shared__ int s[256];
    int t = threadIdx.x, i = blockIdx.x * 256 + t;
    int d = (i < n) ? degcur[i] : 0;
    s[t] = d;
    __syncthreads();
    for (int o = 1; o < 256; o <<= 1) {
        int u = (t >= o) ? s[t - o] : 0;
        __syncthreads();
        s[t] += u;
        __syncthreads();
    }
    int excl = s[t] - d + boff[blockIdx.x];
    if (i < n) {
        off[i] = excl;
        degcur[i] = excl;
    }
    if (blockIdx.x == 0 && t == 0) off[n] = total;
}

__global__ __launch_bounds__(256) void fill_k(const int* __restrict__ src,
                                              const int* __restrict__ dst,
                                              int* __restrict__ cur,
                                              int* __restrict__ col, int n) {
    int e = blockIdx.x * 256 + threadIdx.x;
    if (e < n) {
        int pos = atomicAdd(&cur[dst[e]], 1);
        col[pos] = src[e];
    }
}

// ---------- weight prep (sum matrices for fused dst-type sums) ----------
__global__ __launch_bounds__(256) void prep_sum_k(
    const float* __restrict__ W1rc, const float* __restrict__ W1rw,
    const float* __restrict__ b1c, const float* __restrict__ b1w,
    const float* __restrict__ W2rc, const float* __restrict__ W2rw,
    const float* __restrict__ b2c, const float* __restrict__ b2w,
    float* __restrict__ W1s, float* __restrict__ W2s,
    float* __restrict__ b1s, float* __restrict__ b2s) {
    int t = blockIdx.x * 256 + threadIdx.x;
    if (t < DD * HH) W1s[t] = W1rc[t] + W1rw[t];
    if (t < HH * HH) W2s[t] = W2rc[t] + W2rw[t];
    if (t < HH) {
        b1s[t] = b1c[t] + b1w[t];
        b2s[t] = b2c[t] + b2w[t];
    }
}

// ---------- dense transforms: W read via wave-uniform (scalar) loads ----------
template <int K>
__device__ inline void mm_uni(const float* xr, const float* __restrict__ W, float* acc) {
#pragma unroll 8
    for (int k = 0; k < K; ++k) {
        float xk = xr[k];
#pragma unroll
        for (int c = 0; c < HH; ++c) acc[c] = fmaf(xk, W[k * HH + c], acc[c]);
    }
}

// layer-1 paper: y_pc = x@W1l_c (bf16); y_pr = x@W1l_r (bf16); hp = x@W1s + b1s (f32 self)
__global__ __launch_bounds__(256) void t_p1_k(
    const float* __restrict__ x,
    const float* __restrict__ Wlc, const float* __restrict__ Wlr,
    const float* __restrict__ Ws, const float* __restrict__ bs,
    u16* __restrict__ y_pc, u16* __restrict__ y_pr, float* __restrict__ hp, int n) {
    int row = blockIdx.x * 256 + threadIdx.x;
    if (row >= n) return;
    float xr[DD];
    const float4* xp = (const float4*)(x + (size_t)row * DD);
#pragma unroll
    for (int i = 0; i < DD / 4; ++i) {
        float4 v = xp[i];
        xr[4 * i] = v.x; xr[4 * i + 1] = v.y; xr[4 * i + 2] = v.z; xr[4 * i + 3] = v.w;
    }
    float acc[HH];
#pragma unroll
    for (int c = 0; c < HH; ++c) acc[c] = 0.f;
    mm_uni<DD>(xr, Wlc, acc);
    store_bf16_row(y_pc + (size_t)row * HH, acc);
#pragma unroll
    for (int c = 0; c < HH; ++c) acc[c] = 0.f;
    mm_uni<DD>(xr, Wlr, acc);
    store_bf16_row(y_pr + (size_t)row * HH, acc);
#pragma unroll
    for (int c = 0; c < HH; ++c) acc[c] = bs[c];
    mm_uni<DD>(xr, Ws, acc);
    store_f32_row(hp + (size_t)row * HH, acc);
}

// layer-1 author: y_aw = x@W1l_w (bf16); ha = x@W1r_rev + b1_rev (f32 self)
__global__ __launch_bounds__(256) void t_a1_k(
    const float* __restrict__ x,
    const float* __restrict__ Wlw, const float* __restrict__ Wrr,
    const float* __restrict__ br,
    u16* __restrict__ y_aw, float* __restrict__ ha, int n) {
    int row = blockIdx.x * 256 + threadIdx.x;
    if (row >= n) return;
    float xr[DD];
    const float4* xp = (const float4*)(x + (size_t)row * DD);
#pragma unroll
    for (int i = 0; i < DD / 4; ++i) {
        float4 v = xp[i];
        xr[4 * i] = v.x; xr[4 * i + 1] = v.y; xr[4 * i + 2] = v.z; xr[4 * i + 3] = v.w;
    }
    float acc[HH];
#pragma unroll
    for (int c = 0; c < HH; ++c) acc[c] = 0.f;
    mm_uni<DD>(xr, Wlw, acc);
    store_bf16_row(y_aw + (size_t)row * HH, acc);
#pragma unroll
    for (int c = 0; c < HH; ++c) acc[c] = br[c];
    mm_uni<DD>(xr, Wrr, acc);
    store_f32_row(ha + (size_t)row * HH, acc);
}

// layer-2 paper: r=relu(hp); z=r@W2l_c (bf16); hp <- r@W2s + b2s (f32 self, in-place)
__global__ __launch_bounds__(256) void t_p2_k(
    float* __restrict__ hp,
    const float* __restrict__ Wl, const float* __restrict__ Ws,
    const float* __restrict__ bs,
    u16* __restrict__ z, int n) {
    int row = blockIdx.x * 256 + threadIdx.x;
    if (row >= n) return;
    float xr[HH];
    const float4* xp = (const float4*)(hp + (size_t)row * HH);
#pragma unroll
    for (int i = 0; i < HH / 4; ++i) {
        float4 v = xp[i];
        xr[4 * i]     = v.x > 0.f ? v.x : 0.f;
        xr[4 * i + 1] = v.y > 0.f ? v.y : 0.f;
        xr[4 * i + 2] = v.z > 0.f ? v.z : 0.f;
        xr[4 * i + 3] = v.w > 0.f ? v.w : 0.f;
    }
    float acc[HH];
#pragma unroll
    for (int c = 0; c < HH; ++c) acc[c] = 0.f;
    mm_uni<HH>(xr, Wl, acc);
    store_bf16_row(z + (size_t)row * HH, acc);
#pragma unroll
    for (int c = 0; c < HH; ++c) acc[c] = bs[c];
    mm_uni<HH>(xr, Ws, acc);
    store_f32_row(hp + (size_t)row * HH, acc);
}

// layer-2 author: z_a = relu(ha)@W2l_w (bf16)
__global__ __launch_bounds__(256) void t_a2_k(
    const float* __restrict__ ha, const float* __restrict__ Wl,
    u16* __restrict__ z, int n) {
    int row = blockIdx.x * 256 + threadIdx.x;
    if (row >= n) return;
    float xr[HH];
    const float4* xp = (const float4*)(ha + (size_t)row * HH);
#pragma unroll
    for (int i = 0; i < HH / 4; ++i) {
        float4 v = xp[i];
        xr[4 * i]     = v.x > 0.f ? v.x : 0.f;
        xr[4 * i + 1] = v.y > 0.f ? v.y : 0.f;
        xr[4 * i + 2] = v.z > 0.f ? v.z : 0.f;
        xr[4 * i + 3] = v.w > 0.f ? v.w : 0.f;
    }
    float acc[HH];
#pragma unroll
    for (int c = 0; c < HH; ++c) acc[c] = 0.f;
    mm_uni<HH>(xr, Wl, acc);
    store_bf16_row(z + (size_t)row * HH, acc);
}

// ---------- CSR gather aggregation (no atomics) ----------
__device__ inline float gsum(const u16* __restrict__ y, const int* __restrict__ col,
                             int j0, int j1, int lane) {
    float a = 0.f;
    int j = j0;
    for (; j + 1 < j1; j += 2) {       // unroll 2: overlap col->y dependent chains
        int s0 = col[j], s1 = col[j + 1];
        a += bf2f(y[(size_t)s0 * HH + lane]);
        a += bf2f(y[(size_t)s1 * HH + lane]);
    }
    if (j < j1) a += bf2f(y[(size_t)col[j] * HH + lane]);
    return a;
}

// paper dst: out[d] = self[d] + mean_c(y_c) + mean_w(y_w)  (half-wave per node, lane=channel)
__global__ __launch_bounds__(256) void agg_p_k(
    const u16* __restrict__ y_c, const u16* __restrict__ y_w,
    const int* __restrict__ off_c, const int* __restrict__ col_c,
    const int* __restrict__ off_w, const int* __restrict__ col_w,
    const float* __restrict__ self, float* __restrict__ out, int n) {
    int t = threadIdx.x;
    int lane = t & 31;
    int d = blockIdx.x * 8 + (t >> 5);
    if (d >= n) return;
    int c0 = off_c[d], c1 = off_c[d + 1];
    int w0 = off_w[d], w1 = off_w[d + 1];
    float ac = gsum(y_c, col_c, c0, c1, lane);
    float aw = gsum(y_w, col_w, w0, w1, lane);
    int dc = c1 - c0, dw = w1 - w0;
    float invc = 1.f / (float)(dc > 1 ? dc : 1);
    float invw = 1.f / (float)(dw > 1 ? dw : 1);
    size_t o = (size_t)d * HH + lane;
    out[o] = self[o] + ac * invc + aw * invw;
}

// author dst: ha[d] += mean_r(y)  (in-place)
__global__ __launch_bounds__(256) void agg_a_k(
    const u16* __restrict__ y, const int* __restrict__ off,
    const int* __restrict__ col, float* __restrict__ ha, int n) {
    int t = threadIdx.x;
    int lane = t & 31;
    int d = blockIdx.x * 8 + (t >> 5);
    if (d >= n) return;
    int j0 = off[d], j1 = off[d + 1];
    float a = gsum(y, col, j0, j1, lane);
    int dg = j1 - j0;
    float inv = 1.f / (float)(dg > 1 ? dg : 1);
    size_t o = (size_t)d * HH + lane;
    ha[o] = ha[o] + a * inv;
}

extern "C" void kernel_launch(void* const* d_in, const int* in_sizes, int n_in,
                              void* d_out, int out_size, void* d_ws, size_t ws_size,
                              hipStream_t stream) {
    const float* x_p  = (const float*)d_in[0];
    const float* x_a  = (const float*)d_in[1];
    const int* c_src  = (const int*)d_in[2];
    const int* c_dst  = (const int*)d_in[3];
    const int* w_src  = (const int*)d_in[4];
    const int* w_dst  = (const int*)d_in[5];
    const int* r_src  = (const int*)d_in[6];
    const int* r_dst  = (const int*)d_in[7];
    const float* W1l_c = (const float*)d_in[8];
    const float* W1r_c = (const float*)d_in[9];
    const float* b1_c  = (const float*)d_in[10];
    const float* W1l_w = (const float*)d_in[11];
    const float* W1r_w = (const float*)d_in[12];
    const float* b1_w  = (const float*)d_in[13];
    const float* W1l_r = (const float*)d_in[14];
    const float* W1r_r = (const float*)d_in[15];
    const float* b1_r  = (const float*)d_in[16];
    const float* W2l_c = (const float*)d_in[17];
    const float* W2r_c = (const float*)d_in[18];
    const float* b2_c  = (const float*)d_in[19];
    const float* W2l_w = (const float*)d_in[20];
    const float* W2r_w = (const float*)d_in[21];
    const float* b2_w  = (const float*)d_in[22];

    // ---- workspace layout ----
    // ints: off_c[N_P+1] off_w[N_P+1] off_r[N_A+1] cur_c[N_P] cur_w[N_P] cur_r[N_A]
    //       col_c[NE] col_w[NE] col_r[NE] bsum[1024] boff[1024]
    // f32 : W1s[64*32] W2s[32*32] b1s[32] b2s[32] hp[N_P*32] ha[N_A*32]
    // bf16: y_pc[N_P*32] y_pr[N_P*32] y_aw[N_A*32]   (z_p=y_pc, z_a=y_aw reuse)
    int* wsi   = (int*)d_ws;
    int* off_c = wsi;
    int* off_w = off_c + (N_P + 1);
    int* off_r = off_w + (N_P + 1);
    int* cur_c = off_r + (N_A + 1);
    int* cur_w = cur_c + N_P;
    int* cur_r = cur_w + N_P;
    int* col_c = cur_r + N_A;
    int* col_w = col_c + NE;
    int* col_r = col_w + NE;
    int* bsum  = col_r + NE;
    int* boff  = bsum + 1024;
    uintptr_t fbase = ((uintptr_t)(boff + 1024) + 15) & ~(uintptr_t)15;
    float* W1s = (float*)fbase;                 // 2048
    float* W2s = W1s + DD * HH;                 // 1024
    float* b1s = W2s + HH * HH;                 // 32
    float* b2s = b1s + HH;                      // 32
    float* hp  = b2s + HH;                      // N_P*32  (16B-aligned: 3136*4 % 16 == 0)
    float* ha  = hp + (size_t)N_P * HH;         // N_A*32
    u16* y_pc  = (u16*)(ha + (size_t)N_A * HH); // N_P*32
    u16* y_pr  = y_pc + (size_t)N_P * HH;       // N_P*32
    u16* y_aw  = y_pr + (size_t)N_P * HH;       // N_A*32
    u16* z_p   = y_pc;
    u16* z_a   = y_aw;
    float* outp = (float*)d_out;

    const size_t need = ((uintptr_t)(y_aw + (size_t)N_A * HH)) - (uintptr_t)d_ws;
    if (ws_size < need) return;  // fail loudly (validation) instead of OOB

    const int NBP = (N_P + 255) / 256;   // 782
    const int NBA = (N_A + 255) / 256;   // 391
    const int EB  = (NE + 255) / 256;

    // zero degree/cursor block (contiguous)
    hipMemsetAsync(cur_c, 0, (size_t)(2 * N_P + N_A) * sizeof(int), stream);
    prep_sum_k<<<8, 256, 0, stream>>>(W1r_c, W1r_w, b1_c, b1_w, W2r_c, W2r_w, b2_c, b2_w,
                                      W1s, W2s, b1s, b2s);

    // degree counts
    count_deg_k<<<EB, 256, 0, stream>>>(c_dst, cur_c, NE);
    count_deg_k<<<EB, 256, 0, stream>>>(w_dst, cur_w, NE);
    count_deg_k<<<EB, 256, 0, stream>>>(r_dst, cur_r, NE);

    // CSR: cites
    block_sum_k<<<NBP, 256, 0, stream>>>(cur_c, bsum, N_P);
    scan_chunks_k<<<1, 256, 0, stream>>>(bsum, boff, NBP);
    expand_k<<<NBP, 256, 0, stream>>>(cur_c, boff, off_c, N_P, NE);
    fill_k<<<EB, 256, 0, stream>>>(c_src, c_dst, cur_c, col_c, NE);
    // CSR: writes
    block_sum_k<<<NBP, 256, 0, stream>>>(cur_w, bsum, N_P);
    scan_chunks_k<<<1, 256, 0, stream>>>(bsum, boff, NBP);
    expand_k<<<NBP, 256, 0, stream>>>(cur_w, boff, off_w, N_P, NE);
    fill_k<<<EB, 256, 0, stream>>>(w_src, w_dst, cur_w, col_w, NE);
    // CSR: rev
    block_sum_k<<<NBA, 256, 0, stream>>>(cur_r, bsum, N_A);
    scan_chunks_k<<<1, 256, 0, stream>>>(bsum, boff, NBA);
    expand_k<<<NBA, 256, 0, stream>>>(cur_r, boff, off_r, N_A, NE);
    fill_k<<<EB, 256, 0, stream>>>(r_src, r_dst, cur_r, col_r, NE);

    // layer-1 transforms (scalar-W, no LDS)
    t_p1_k<<<NBP, 256, 0, stream>>>(x_p, W1l_c, W1l_r, W1s, b1s, y_pc, y_pr, hp, N_P);
    t_a1_k<<<NBA, 256, 0, stream>>>(x_a, W1l_w, W1r_r, b1_r, y_aw, ha, N_A);

    // layer-1 aggregation (gather, no atomics)
    agg_p_k<<<(N_P + 7) / 8, 256, 0, stream>>>(y_pc, y_aw, off_c, col_c, off_w, col_w,
                                               hp, hp, N_P);
    agg_a_k<<<(N_A + 7) / 8, 256, 0, stream>>>(y_pr, off_r, col_r, ha, N_A);

    // layer-2 transforms
    t_p2_k<<<NBP, 256, 0, stream>>>(hp, W2l_c, W2s, b2s, z_p, N_P);
    t_a2_k<<<NBA, 256, 0, stream>>>(ha, W2l_w, z_a, N_A);

    // layer-2 aggregation -> d_out
    agg_p_k<<<(N_P + 7) / 8, 256, 0, stream>>>(z_p, z_a, off_c, col_c, off_w, col_w,
                                               hp, outp, N_P);
}

// Round 6
// 838.001 us; speedup vs baseline: 1.1758x; 1.0593x over previous
//
#include <hip/hip_runtime.h>

typedef unsigned short u16;
typedef unsigned int   u32;

#define N_P 200000
#define N_A 100000
#define DD  64
#define HH  32
#define NE  1000000
#define NBP 782          // (N_P+255)/256
#define NBA 391          // (N_A+255)/256
#define EB  3907         // (NE+255)/256

// ---------- bf16 helpers (RNE) ----------
__device__ inline float bf2f(u16 u) { return __uint_as_float(((u32)u) << 16); }
__device__ inline u16 f2bf(float f) {
    u32 u = __float_as_uint(f);
    u += 0x7fffu + ((u >> 16) & 1u);
    return (u16)(u >> 16);
}

// ---------- CSR build (3 relations fused per kernel) ----------
__global__ __launch_bounds__(256) void count3_k(
    const int* __restrict__ d0, const int* __restrict__ d1, const int* __restrict__ d2,
    int* __restrict__ g0, int* __restrict__ g1, int* __restrict__ g2) {
    int e = blockIdx.x * 256 + threadIdx.x;
    const int* d; int* g;
    if (blockIdx.y == 0)      { d = d0; g = g0; }
    else if (blockIdx.y == 1) { d = d1; g = g1; }
    else                      { d = d2; g = g2; }
    if (e < NE) atomicAdd(&g[d[e]], 1);
}

__global__ __launch_bounds__(256) void bsum3_k(
    const int* __restrict__ a0, const int* __restrict__ a1, const int* __restrict__ a2,
    int* __restrict__ bs) {
    __shared__ int s[256];
    int rel = blockIdx.y;
    const int* a = rel == 0 ? a0 : rel == 1 ? a1 : a2;
    int n = (rel == 2) ? N_A : N_P;
    int t = threadIdx.x, i = blockIdx.x * 256 + t;
    s[t] = (i < n) ? a[i] : 0;
    __syncthreads();
    for (int o = 128; o > 0; o >>= 1) {
        if (t < o) s[t] += s[t + o];
        __syncthreads();
    }
    if (t == 0) bs[rel * 1024 + blockIdx.x] = s[0];
}

// one block per relation; 256 threads × 4 items serial + Hillis-Steele
__global__ __launch_bounds__(256) void scan3_k(const int* __restrict__ bs,
                                               int* __restrict__ bo) {
    __shared__ int s[256];
    int rel = blockIdx.x;
    int n = (rel == 2) ? NBA : NBP;
    const int* src = bs + rel * 1024;
    int* dst = bo + rel * 1024;
    int t = threadIdx.x;
    int v[4]; int tot = 0;
#pragma unroll
    for (int i = 0; i < 4; ++i) {
        int idx = t * 4 + i;
        v[i] = (idx < n) ? src[idx] : 0;
        tot += v[i];
    }
    s[t] = tot;
    __syncthreads();
    for (int o = 1; o < 256; o <<= 1) {
        int u = (t >= o) ? s[t - o] : 0;
        __syncthreads();
        s[t] += u;
        __syncthreads();
    }
    int run = s[t] - tot;
#pragma unroll
    for (int i = 0; i < 4; ++i) {
        int idx = t * 4 + i;
        if (idx < n) dst[idx] = run;
        run += v[i];
    }
}

__global__ __launch_bounds__(256) void expand3_k(
    int* __restrict__ c0, int* __restrict__ c1, int* __restrict__ c2,
    int* __restrict__ o0, int* __restrict__ o1, int* __restrict__ o2,
    const int* __restrict__ bo) {
    __shared__ int s[256];
    int rel = blockIdx.y;
    int* degcur; int* off; int n;
    if (rel == 0)      { degcur = c0; off = o0; n = N_P; }
    else if (rel == 1) { degcur = c1; off = o1; n = N_P; }
    else               { degcur = c2; off = o2; n = N_A; }
    int t = threadIdx.x, i = blockIdx.x * 256 + t;
    int d = (i < n) ? degcur[i] : 0;
    s[t] = d;
    __syncthreads();
    for (int o = 1; o < 256; o <<= 1) {
        int u = (t >= o) ? s[t - o] : 0;
        __syncthreads();
        s[t] += u;
        __syncthreads();
    }
    int excl = s[t] - d + bo[rel * 1024 + blockIdx.x];
    if (i < n) {
        off[i] = excl;
        degcur[i] = excl;
    }
    if (blockIdx.x == 0 && t == 0) off[n] = NE;
}

__global__ __launch_bounds__(256) void fill3_k(
    const int* __restrict__ s0, const int* __restrict__ d0,
    const int* __restrict__ s1, const int* __restrict__ d1,
    const int* __restrict__ s2, const int* __restrict__ d2,
    int* __restrict__ c0, int* __restrict__ c1, int* __restrict__ c2,
    int* __restrict__ l0, int* __restrict__ l1, int* __restrict__ l2) {
    int e = blockIdx.x * 256 + threadIdx.x;
    const int *src, *dst; int *cur, *col;
    if (blockIdx.y == 0)      { src = s0; dst = d0; cur = c0; col = l0; }
    else if (blockIdx.y == 1) { src = s1; dst = d1; cur = c1; col = l1; }
    else                      { src = s2; dst = d2; cur = c2; col = l2; }
    if (e < NE) {
        int pos = atomicAdd(&cur[dst[e]], 1);
        col[pos] = src[e];
    }
}

// ---------- weight prep ----------
__global__ __launch_bounds__(256) void prep_sum_k(
    const float* __restrict__ W1rc, const float* __restrict__ W1rw,
    const float* __restrict__ b1c, const float* __restrict__ b1w,
    const float* __restrict__ W2rc, const float* __restrict__ W2rw,
    const float* __restrict__ b2c, const float* __restrict__ b2w,
    float* __restrict__ W1s, float* __restrict__ W2s,
    float* __restrict__ b1s, float* __restrict__ b2s) {
    int t = blockIdx.x * 256 + threadIdx.x;
    if (t < DD * HH) W1s[t] = W1rc[t] + W1rw[t];
    if (t < HH * HH) W2s[t] = W2rc[t] + W2rw[t];
    if (t < HH) {
        b1s[t] = b1c[t] + b1w[t];
        b2s[t] = b2c[t] + b2w[t];
    }
}

// ---------- dense transform core (wave-uniform W -> scalar loads) ----------
template <int K>
__device__ inline void mm_uni(const float* xr, const float* __restrict__ W, float* acc) {
#pragma unroll 8
    for (int k = 0; k < K; ++k) {
        float xk = xr[k];
#pragma unroll
        for (int c = 0; c < HH; ++c) acc[c] = fmaf(xk, W[k * HH + c], acc[c]);
    }
}

// ---------- LDS-staged fully-coalesced epilogues ----------
// sbuf: 256*33 floats (33792 B). bf16 staging uses dword stride 17 (conflict-free);
// f32 staging uses float stride 33 (conflict-free). Cooperative store: each store
// instruction writes 16 B/lane at contiguous addresses -> full 4 KB lines, no
// write-allocate fetch, no partial-line write-back.
__device__ inline void coop_store_bf16(float* sbuf, int t, const float* acc,
                                       bool valid, int nv, u16* grow) {
    if (valid) {
        u32* sp = (u32*)sbuf + t * 17;
#pragma unroll
        for (int i = 0; i < 16; ++i)
            sp[i] = (u32)f2bf(acc[2 * i]) | ((u32)f2bf(acc[2 * i + 1]) << 16);
    }
    __syncthreads();
    u32* g = (u32*)grow;
#pragma unroll
    for (int p = 0; p < 4; ++p) {
        int i = p * 256 + t;            // 16-B chunk id, 0..1023
        int row = i >> 2, off = (i & 3) * 4;
        if (row < nv) {
            const u32* q = (const u32*)sbuf + row * 17 + off;
            *(uint4*)(g + (size_t)i * 4) = make_uint4(q[0], q[1], q[2], q[3]);
        }
    }
    __syncthreads();
}

__device__ inline void coop_store_f32(float* sbuf, int t, const float* acc,
                                      bool valid, int nv, float* grow) {
    if (valid) {
        float* sp = sbuf + t * 33;
#pragma unroll
        for (int c = 0; c < HH; ++c) sp[c] = acc[c];
    }
    __syncthreads();
#pragma unroll
    for (int p = 0; p < 8; ++p) {
        int i = p * 256 + t;            // 16-B chunk id, 0..2047
        int row = i >> 3, off = (i & 7) * 4;
        if (row < nv) {
            const float* q = sbuf + row * 33 + off;
            *(float4*)(grow + (size_t)i * 4) = make_float4(q[0], q[1], q[2], q[3]);
        }
    }
    __syncthreads();
}

// ---------- layer-1 transforms, paper+author fused ----------
__global__ __launch_bounds__(256) void t1_k(
    const float* __restrict__ xp, const float* __restrict__ xa,
    const float* __restrict__ Wlc, const float* __restrict__ Wlr,
    const float* __restrict__ W1s, const float* __restrict__ b1s,
    const float* __restrict__ Wlw, const float* __restrict__ Wrr,
    const float* __restrict__ b1r,
    u16* __restrict__ y_pc, u16* __restrict__ y_pr, u16* __restrict__ y_aw,
    float* __restrict__ hp, float* __restrict__ ha) {
    __shared__ float sbuf[256 * 33];
    int t = threadIdx.x;
    float xr[DD];
    float acc[HH];
    if (blockIdx.x < NBP) {
        int row0 = blockIdx.x * 256;
        int nv = min(256, N_P - row0);
        bool valid = t < nv;
        if (valid) {
            const float4* xv = (const float4*)(xp + (size_t)(row0 + t) * DD);
#pragma unroll
            for (int i = 0; i < DD / 4; ++i) {
                float4 v = xv[i];
                xr[4 * i] = v.x; xr[4 * i + 1] = v.y; xr[4 * i + 2] = v.z; xr[4 * i + 3] = v.w;
            }
        }
#pragma unroll
        for (int c = 0; c < HH; ++c) acc[c] = 0.f;
        if (valid) mm_uni<DD>(xr, Wlc, acc);
        coop_store_bf16(sbuf, t, acc, valid, nv, y_pc + (size_t)row0 * HH);
#pragma unroll
        for (int c = 0; c < HH; ++c) acc[c] = 0.f;
        if (valid) mm_uni<DD>(xr, Wlr, acc);
        coop_store_bf16(sbuf, t, acc, valid, nv, y_pr + (size_t)row0 * HH);
#pragma unroll
        for (int c = 0; c < HH; ++c) acc[c] = b1s[c];
        if (valid) mm_uni<DD>(xr, W1s, acc);
        coop_store_f32(sbuf, t, acc, valid, nv, hp + (size_t)row0 * HH);
    } else {
        int row0 = (blockIdx.x - NBP) * 256;
        int nv = min(256, N_A - row0);
        bool valid = t < nv;
        if (valid) {
            const float4* xv = (const float4*)(xa + (size_t)(row0 + t) * DD);
#pragma unroll
            for (int i = 0; i < DD / 4; ++i) {
                float4 v = xv[i];
                xr[4 * i] = v.x; xr[4 * i + 1] = v.y; xr[4 * i + 2] = v.z; xr[4 * i + 3] = v.w;
            }
        }
#pragma unroll
        for (int c = 0; c < HH; ++c) acc[c] = 0.f;
        if (valid) mm_uni<DD>(xr, Wlw, acc);
        coop_store_bf16(sbuf, t, acc, valid, nv, y_aw + (size_t)row0 * HH);
#pragma unroll
        for (int c = 0; c < HH; ++c) acc[c] = b1r[c];
        if (valid) mm_uni<DD>(xr, Wrr, acc);
        coop_store_f32(sbuf, t, acc, valid, nv, ha + (size_t)row0 * HH);
    }
}

// ---------- layer-2 transforms, paper+author fused ----------
__global__ __launch_bounds__(256) void t2_k(
    float* __restrict__ hp, const float* __restrict__ ha,
    const float* __restrict__ Wlc, const float* __restrict__ W2s,
    const float* __restrict__ b2s, const float* __restrict__ Wlw,
    u16* __restrict__ z_p, u16* __restrict__ z_a) {
    __shared__ float sbuf[256 * 33];
    int t = threadIdx.x;
    float xr[HH];
    float acc[HH];
    if (blockIdx.x < NBP) {
        int row0 = blockIdx.x * 256;
        int nv = min(256, N_P - row0);
        bool valid = t < nv;
        if (valid) {
            const float4* xv = (const float4*)(hp + (size_t)(row0 + t) * HH);
#pragma unroll
            for (int i = 0; i < HH / 4; ++i) {
                float4 v = xv[i];
                xr[4 * i]     = v.x > 0.f ? v.x : 0.f;
                xr[4 * i + 1] = v.y > 0.f ? v.y : 0.f;
                xr[4 * i + 2] = v.z > 0.f ? v.z : 0.f;
                xr[4 * i + 3] = v.w > 0.f ? v.w : 0.f;
            }
        }
#pragma unroll
        for (int c = 0; c < HH; ++c) acc[c] = 0.f;
        if (valid) mm_uni<HH>(xr, Wlc, acc);
        coop_store_bf16(sbuf, t, acc, valid, nv, z_p + (size_t)row0 * HH);
#pragma unroll
        for (int c = 0; c < HH; ++c) acc[c] = b2s[c];
        if (valid) mm_uni<HH>(xr, W2s, acc);
        coop_store_f32(sbuf, t, acc, valid, nv, hp + (size_t)row0 * HH); // in-place: block owns rows
    } else {
        int row0 = (blockIdx.x - NBP) * 256;
        int nv = min(256, N_A - row0);
        bool valid = t < nv;
        if (valid) {
            const float4* xv = (const float4*)(ha + (size_t)(row0 + t) * HH);
#pragma unroll
            for (int i = 0; i < HH / 4; ++i) {
                float4 v = xv[i];
                xr[4 * i]     = v.x > 0.f ? v.x : 0.f;
                xr[4 * i + 1] = v.y > 0.f ? v.y : 0.f;
                xr[4 * i + 2] = v.z > 0.f ? v.z : 0.f;
                xr[4 * i + 3] = v.w > 0.f ? v.w : 0.f;
            }
        }
#pragma unroll
        for (int c = 0; c < HH; ++c) acc[c] = 0.f;
        if (valid) mm_uni<HH>(xr, Wlw, acc);
        coop_store_bf16(sbuf, t, acc, valid, nv, z_a + (size_t)row0 * HH);
    }
}

// ---------- CSR gather aggregation ----------
__device__ inline float gsum(const u16* __restrict__ y, const int* __restrict__ col,
                             int j0, int j1, int lane) {
    float a = 0.f;
    int j = j0;
    for (; j + 1 < j1; j += 2) {
        int s0 = col[j], s1 = col[j + 1];
        a += bf2f(y[(size_t)s0 * HH + lane]);
        a += bf2f(y[(size_t)s1 * HH + lane]);
    }
    if (j < j1) a += bf2f(y[(size_t)col[j] * HH + lane]);
    return a;
}

#define NBAGP 25000      // (N_P+7)/8
#define NBAGA 12500      // (N_A+7)/8

// layer-1: paper (cites+writes into hp) and author (rev into ha), fused
__global__ __launch_bounds__(256) void agg1_k(
    const u16* __restrict__ y_pc, const u16* __restrict__ y_aw,
    const u16* __restrict__ y_pr,
    const int* __restrict__ off_c, const int* __restrict__ col_c,
    const int* __restrict__ off_w, const int* __restrict__ col_w,
    const int* __restrict__ off_r, const int* __restrict__ col_r,
    float* __restrict__ hp, float* __restrict__ ha) {
    int t = threadIdx.x;
    int lane = t & 31;
    if (blockIdx.x < NBAGP) {
        int d = blockIdx.x * 8 + (t >> 5);
        if (d >= N_P) return;
        int c0 = off_c[d], c1 = off_c[d + 1];
        int w0 = off_w[d], w1 = off_w[d + 1];
        float ac = gsum(y_pc, col_c, c0, c1, lane);
        float aw = gsum(y_aw, col_w, w0, w1, lane);
        int dc = c1 - c0, dw = w1 - w0;
        float invc = 1.f / (float)(dc > 1 ? dc : 1);
        float invw = 1.f / (float)(dw > 1 ? dw : 1);
        size_t o = (size_t)d * HH + lane;
        hp[o] = hp[o] + ac * invc + aw * invw;
    } else {
        int d = (blockIdx.x - NBAGP) * 8 + (t >> 5);
        if (d >= N_A) return;
        int j0 = off_r[d], j1 = off_r[d + 1];
        float a = gsum(y_pr, col_r, j0, j1, lane);
        int dg = j1 - j0;
        float inv = 1.f / (float)(dg > 1 ? dg : 1);
        size_t o = (size_t)d * HH + lane;
        ha[o] = ha[o] + a * inv;
    }
}

// layer-2: paper only, into d_out
__global__ __launch_bounds__(256) void agg2_k(
    const u16* __restrict__ z_p, const u16* __restrict__ z_a,
    const int* __restrict__ off_c, const int* __restrict__ col_c,
    const int* __restrict__ off_w, const int* __restrict__ col_w,
    const float* __restrict__ self, float* __restrict__ out) {
    int t = threadIdx.x;
    int lane = t & 31;
    int d = blockIdx.x * 8 + (t >> 5);
    if (d >= N_P) return;
    int c0 = off_c[d], c1 = off_c[d + 1];
    int w0 = off_w[d], w1 = off_w[d + 1];
    float ac = gsum(z_p, col_c, c0, c1, lane);
    float aw = gsum(z_a, col_w, w0, w1, lane);
    int dc = c1 - c0, dw = w1 - w0;
    float invc = 1.f / (float)(dc > 1 ? dc : 1);
    float invw = 1.f / (float)(dw > 1 ? dw : 1);
    size_t o = (size_t)d * HH + lane;
    out[o] = self[o] + ac * invc + aw * invw;
}

extern "C" void kernel_launch(void* const* d_in, const int* in_sizes, int n_in,
                              void* d_out, int out_size, void* d_ws, size_t ws_size,
                              hipStream_t stream) {
    const float* x_p  = (const float*)d_in[0];
    const float* x_a  = (const float*)d_in[1];
    const int* c_src  = (const int*)d_in[2];
    const int* c_dst  = (const int*)d_in[3];
    const int* w_src  = (const int*)d_in[4];
    const int* w_dst  = (const int*)d_in[5];
    const int* r_src  = (const int*)d_in[6];
    const int* r_dst  = (const int*)d_in[7];
    const float* W1l_c = (const float*)d_in[8];
    const float* W1r_c = (const float*)d_in[9];
    const float* b1_c  = (const float*)d_in[10];
    const float* W1l_w = (const float*)d_in[11];
    const float* W1r_w = (const float*)d_in[12];
    const float* b1_w  = (const float*)d_in[13];
    const float* W1l_r = (const float*)d_in[14];
    const float* W1r_r = (const float*)d_in[15];
    const float* b1_r  = (const float*)d_in[16];
    const float* W2l_c = (const float*)d_in[17];
    const float* W2r_c = (const float*)d_in[18];
    const float* b2_c  = (const float*)d_in[19];
    const float* W2l_w = (const float*)d_in[20];
    const float* W2r_w = (const float*)d_in[21];
    const float* b2_w  = (const float*)d_in[22];

    // ---- workspace layout (same as round 5 + 3x1024 scan buffers) ----
    int* wsi   = (int*)d_ws;
    int* off_c = wsi;
    int* off_w = off_c + (N_P + 1);
    int* off_r = off_w + (N_P + 1);
    int* cur_c = off_r + (N_A + 1);
    int* cur_w = cur_c + N_P;
    int* cur_r = cur_w + N_P;
    int* col_c = cur_r + N_A;
    int* col_w = col_c + NE;
    int* col_r = col_w + NE;
    int* bs    = col_r + NE;            // 3*1024
    int* bo    = bs + 3 * 1024;         // 3*1024
    uintptr_t fbase = ((uintptr_t)(bo + 3 * 1024) + 15) & ~(uintptr_t)15;
    float* W1s = (float*)fbase;                 // 2048
    float* W2s = W1s + DD * HH;                 // 1024
    float* b1s = W2s + HH * HH;                 // 32
    float* b2s = b1s + HH;                      // 32
    float* hp  = b2s + HH;                      // N_P*32
    float* ha  = hp + (size_t)N_P * HH;         // N_A*32
    u16* y_pc  = (u16*)(ha + (size_t)N_A * HH); // N_P*32
    u16* y_pr  = y_pc + (size_t)N_P * HH;       // N_P*32
    u16* y_aw  = y_pr + (size_t)N_P * HH;       // N_A*32
    u16* z_p   = y_pc;
    u16* z_a   = y_aw;
    float* outp = (float*)d_out;

    const size_t need = ((uintptr_t)(y_aw + (size_t)N_A * HH)) - (uintptr_t)d_ws;
    if (ws_size < need) return;

    hipMemsetAsync(cur_c, 0, (size_t)(2 * N_P + N_A) * sizeof(int), stream);
    prep_sum_k<<<8, 256, 0, stream>>>(W1r_c, W1r_w, b1_c, b1_w, W2r_c, W2r_w, b2_c, b2_w,
                                      W1s, W2s, b1s, b2s);

    count3_k<<<dim3(EB, 3), 256, 0, stream>>>(c_dst, w_dst, r_dst, cur_c, cur_w, cur_r);
    bsum3_k<<<dim3(NBP, 3), 256, 0, stream>>>(cur_c, cur_w, cur_r, bs);
    scan3_k<<<3, 256, 0, stream>>>(bs, bo);
    expand3_k<<<dim3(NBP, 3), 256, 0, stream>>>(cur_c, cur_w, cur_r, off_c, off_w, off_r, bo);
    fill3_k<<<dim3(EB, 3), 256, 0, stream>>>(c_src, c_dst, w_src, w_dst, r_src, r_dst,
                                             cur_c, cur_w, cur_r, col_c, col_w, col_r);

    t1_k<<<NBP + NBA, 256, 0, stream>>>(x_p, x_a, W1l_c, W1l_r, W1s, b1s,
                                        W1l_w, W1r_r, b1_r, y_pc, y_pr, y_aw, hp, ha);
    agg1_k<<<NBAGP + NBAGA, 256, 0, stream>>>(y_pc, y_aw, y_pr, off_c, col_c,
                                              off_w, col_w, off_r, col_r, hp, ha);
    t2_k<<<NBP + NBA, 256, 0, stream>>>(hp, ha, W2l_c, W2s, b2s, W2l_w, z_p, z_a);
    agg2_k<<<NBAGP, 256, 0, stream>>>(z_p, z_a, off_c, col_c, off_w, col_w, hp, outp);
}